// Round 11
// baseline (184.452 us; speedup 1.0000x reference)
//
#include <hip/hip_runtime.h>
#include <hip/hip_bf16.h>
#include <stdint.h>

// ---------------- problem constants ----------------
#define LTOK  1025      // 1024 body + 1 cls
#define NROWS 2050      // B * LTOK
#define DM    512
#define DIN   1024
#define DST   128
#define NHEAD 16
#define HDIM  64
#define CDIM  1280      // DIN + 2*DST
#define EPROJ 2320      // 2*DIN + 2*DST + NHEAD
#define QC    64        // SSD chunk length
#define NCH   17        // ceil(1025/64)

// ---------------- workspace layout (float offsets), ws = 256 MiB ----------------
#define O_RIDX   0          // int32 x 514 (reserve 1024)
#define O_CB     1024
#define O_CLS    1536
#define O_C1B    2048
#define O_DTB    3328
#define O_ALOG   3344
#define O_DV     3360
#define O_RMSW   3376
#define O_LNG    4400
#define O_LNB    4912
#define O_CW     5440       // (dead)
#define O_IPW    103744     // bf16 (ushort) 2320x512
#define O_OPW    1291584    // bf16 (ushort)
#define O_C1W    1815872
#define O_CX     1820992    // (dead)
#define O_ZX     1952064    // bf16 (ushort)
#define O_XBC    6708064    // bf16 (ushort)
#define O_DT     9332064
#define O_LGA    9364864    // log(dA) = dt * (-exp(A_log))
#define O_Y      9397664    // f32
#define O_X3     10447264   // bf16 (ushort); im2col A (k' layout), later gated bf16 G
#define O_OUTG   11496864   // (dead)
#define O_SL     11760032   // chunk states BF16 (ushort): 32*17*8192 ushorts
#define O_CLA    16216480   // within-chunk cumsum logdA: 32*17*64
#define O_SL2    16251296   // bf16 prefix states: 32*17*8192 ushorts
#define O_KEEP   18479520   // uint8 keep flags x 2050
#define O_OUTP   18480128   // f32 out_proj partials: 4 x 514*512
#define O_CWT    19532800   // bf16 CW^T reordered (192x512): row k' = tap*64 + i
#define O_W2     19581952   // bf16 W2 (2320x192, k' order) = 445440 ushorts
#define O_BIAS2  19804672   // f32 bias2 (2320)

// ---------------- output layout (FLOAT32 elements) ----------------
#define OO_MASK 263168
#define OO_IDR  265216
#define OO_IDK  267264

typedef __attribute__((ext_vector_type(8))) short short8;
typedef __attribute__((ext_vector_type(8))) unsigned short ushortx8;
typedef __attribute__((ext_vector_type(4))) float floatx4;

__device__ __forceinline__ short f2bs(float f) {
  union { float f; uint32_t u; } v; v.f = f;
  uint32_t r = (v.u + 0x7FFFu + ((v.u >> 16) & 1u)) >> 16;
  return (short)r;
}
__device__ __forceinline__ float bf2f(uint16_t u) {
  return __uint_as_float(((uint32_t)u) << 16);
}

struct InPtrs { const void* p[14]; };

// ---------------- threefry2x32 (JAX-compatible) ----------------
__device__ __forceinline__ uint32_t rotl32(uint32_t v, int d) {
  return (v << d) | (v >> (32 - d));
}
__device__ void threefry2x32(uint32_t k0, uint32_t k1, uint32_t c0, uint32_t c1,
                             uint32_t& o0, uint32_t& o1) {
  uint32_t ks0 = k0, ks1 = k1, ks2 = 0x1BD11BDAu ^ k0 ^ k1;
  uint32_t x0 = c0 + ks0, x1 = c1 + ks1;
#define TF_R4(a,b,c,d) \
  x0 += x1; x1 = rotl32(x1,a); x1 ^= x0; \
  x0 += x1; x1 = rotl32(x1,b); x1 ^= x0; \
  x0 += x1; x1 = rotl32(x1,c); x1 ^= x0; \
  x0 += x1; x1 = rotl32(x1,d); x1 ^= x0;
  TF_R4(13,15,26,6)  x0 += ks1; x1 += ks2 + 1u;
  TF_R4(17,29,16,24) x0 += ks2; x1 += ks0 + 2u;
  TF_R4(13,15,26,6)  x0 += ks0; x1 += ks1 + 3u;
  TF_R4(17,29,16,24) x0 += ks1; x1 += ks2 + 4u;
  TF_R4(13,15,26,6)  x0 += ks2; x1 += ks0 + 5u;
#undef TF_R4
  o0 = x0; o1 = x1;
}

// ---------------- input dtype detect ----------------
__device__ int detect_is_f32(const uint32_t* w, int nelem) {
  int nw = nelem / 2; if (nw > 16) nw = 16;
  int insane = 0, lozero = 0, anynz = 0;
  for (int i = 0; i < nw; ++i) {
    uint32_t word = w[i];
    if (word != 0u) anynz = 1;
    uint32_t lo = word & 0xffffu;
    if (lo == 0u) { lozero++; continue; }
    float v = __uint_as_float(lo << 16);
    float a = fabsf(v);
    if (!(a >= 1e-8f && a <= 1e4f)) insane++;
  }
  if (insane >= 2) return 1;
  if (lozero == nw && anynz) return 1;
  return 0;
}

// ---------------- convert + RNG/keep + im2col(vec,k'), flattened 1-D grid (2071 blocks) ----------------
// [0,256)       im2col vectorized: 8 rows/block, X3[r][k'] with k' = tap*64 + i
// [256,1416)    IPW convert (t=3), 1160 blocks
// [1416,1928)   OPW convert (t=10), 512 blocks
// [1928,2024)   CWT transpose-reorder (row k' = tap*64 + i), 96 blocks
// [2024,2056)   RNG/keep, 32 blocks
// [2056,2071)   15 small-tensor jobs
__global__ __launch_bounds__(256) void k_convert(InPtrs ptrs, float* ws,
                                                 float* out, int* rowidx) {
  static const int sizes[13] = {98304, 512, 512, 1187840, 5120, 1280,
                                16, 16, 16, 1024, 524288, 512, 512};
  static const int offs[13]  = {O_CW, O_CB, O_CLS, O_IPW, O_C1W, O_C1B,
                                O_DTB, O_ALOG, O_DV, O_RMSW, O_OPW, O_LNG, O_LNB};
  static const int isbf[13]  = {1,0,0,1,0,0,0,0,0,0,1,0,0};
  static const int smallT[15] = {1,2,4,4,4,4,4,5,5,6,7,8,9,11,12};
  static const int smallB[15] = {0,0,0,1,2,3,4,0,1,0,0,0,0,0,0};
  int bx = blockIdx.x;
  int tid = threadIdx.x;

  if (bx < 256) {                                   // im2col vectorized, k' layout
    const uint32_t* xp = (const uint32_t*)ptrs.p[0];
    __shared__ int xf;
    if (tid == 0) xf = detect_is_f32(xp, 131072);
    __syncthreads();
    if (tid < 192) {
      int r = bx * 8 + tid / 24;                    // 0..2047
      int seg = tid % 24;
      int kk = seg >> 3, i0 = (seg & 7) * 8;        // k' = kk*64 + i0
      int b = r >> 10, idx = r & 1023;
      int tt = idx + kk - 1;
      ushortx8 o = {0,0,0,0,0,0,0,0};
      if (tt >= 0 && tt < 1024) {
        long src = ((long)(b * 1024 + tt)) * 64 + i0;
        if (xf) {
          const float* xfp = (const float*)xp;
          float4 f0 = *(const float4*)(xfp + src);
          float4 f1 = *(const float4*)(xfp + src + 4);
          o[0] = (uint16_t)f2bs(f0.x); o[1] = (uint16_t)f2bs(f0.y);
          o[2] = (uint16_t)f2bs(f0.z); o[3] = (uint16_t)f2bs(f0.w);
          o[4] = (uint16_t)f2bs(f1.x); o[5] = (uint16_t)f2bs(f1.y);
          o[6] = (uint16_t)f2bs(f1.z); o[7] = (uint16_t)f2bs(f1.w);
        } else {
          o = *(const ushortx8*)((const uint16_t*)xp + src);
        }
      }
      *(ushortx8*)((uint16_t*)(ws + O_X3) + (long)r * 192 + kk * 64 + i0) = o;
    }
    return;
  }
  bx -= 256;

  int t, blk;
  if (bx < 1160) { t = 3; blk = bx; }
  else {
    bx -= 1160;
    if (bx < 512) { t = 10; blk = bx; }
    else {
      bx -= 512;
      if (bx < 96) {                                // CWT transpose-reorder (conv_emb_w)
        const uint32_t* w = (const uint32_t*)ptrs.p[1];
        __shared__ int sf;
        if (tid == 0) sf = detect_is_f32(w, 98304);
        __syncthreads();
        int base = (bx * 256 + tid) * 4;
        if (base >= 98304) return;
        uint16_t vv[4];
        if (sf) {
          const float4 f = *(const float4*)((const float*)w + base);
          vv[0] = (uint16_t)f2bs(f.x); vv[1] = (uint16_t)f2bs(f.y);
          vv[2] = (uint16_t)f2bs(f.z); vv[3] = (uint16_t)f2bs(f.w);
        } else {
          const uint32_t* s = w + (base >> 1);
          uint32_t w0 = s[0], w1 = s[1];
          vv[0] = (uint16_t)(w0 & 0xffffu); vv[1] = (uint16_t)(w0 >> 16);
          vv[2] = (uint16_t)(w1 & 0xffffu); vv[3] = (uint16_t)(w1 >> 16);
        }
        int o = base / 192, ik = base % 192;        // flat = o*192 + i*3 + tap
        uint16_t* cwt = (uint16_t*)(ws + O_CWT);
#pragma unroll
        for (int j = 0; j < 4; ++j) {
          int ikj = ik + j;
          int kp = (ikj % 3) * 64 + (ikj / 3);      // k' = tap*64 + i
          cwt[(long)kp * 512 + o] = vv[j];
        }
        return;
      }
      bx -= 96;
      if (bx < 32) {                                // RNG / keep / rowidx
        int seg = bx & 15, b = bx >> 4;
        uint8_t* keep = (uint8_t*)(ws + O_KEEP);
        __shared__ float vals[1024];
        uint32_t fk0, fk1;
        threefry2x32(0u, 0u, 0u, 1u, fk0, fk1);     // fold_in(key(0), 1)
#pragma unroll
        for (int k = 0; k < 4; ++k) {
          int i = tid + k * 256;
          uint32_t o0, o1;
          threefry2x32(fk0, fk1, 0u, (uint32_t)(b * 1024 + i), o0, o1);
          uint32_t bits = o0 ^ o1;
          vals[i] = __uint_as_float((bits >> 9) | 0x3f800000u) - 1.0f;
        }
        __syncthreads();
        int tg = seg * 64 + (tid >> 2);
        int qq = tid & 3;
        float v = vals[tg];
        int r = 0;
        int j0 = qq * 256;
        for (int it = 0; it < 256; ++it) {
          int j = j0 + ((it + qq * 8) & 255);
          float vj = vals[j];
          r += (vj < v || (vj == v && j < tg)) ? 1 : 0;
        }
        r += __shfl_xor(r, 1, 64);
        r += __shfl_xor(r, 2, 64);
        if (qq == 0) {
          out[OO_IDR + b * 1024 + tg] = (float)r;
          out[OO_MASK + b * 1024 + tg] = (r < 256) ? 0.0f : 1.0f;
          keep[b * LTOK + tg] = (r < 256) ? 1 : 0;
          if (r < 256) {
            out[OO_IDK + b * 256 + r] = (float)tg;
            rowidx[b * 257 + r] = b * LTOK + tg;
          }
          if (tg == 0) {
            rowidx[b * 257 + 256] = b * LTOK + 1024;
            keep[b * LTOK + 1024] = 1;
          }
        }
        return;
      }
      bx -= 32;
      if (bx >= 15) return;
      t = smallT[bx]; blk = smallB[bx];
    }
  }

  // generic conversion job (t, blk)
  int n = sizes[t];
  const uint32_t* w = (const uint32_t*)ptrs.p[t + 1];
  __shared__ int sf;
  if (tid == 0) sf = detect_is_f32(w, n);
  __syncthreads();
  int base = (blk * 256 + tid) * 4;
  if (base >= n) return;
  if (isbf[t]) {
    ushort4 o;
    if (sf) {
      const float4 vv = *(const float4*)((const float*)w + base);
      o.x = (uint16_t)f2bs(vv.x); o.y = (uint16_t)f2bs(vv.y);
      o.z = (uint16_t)f2bs(vv.z); o.w = (uint16_t)f2bs(vv.w);
    } else {
      const uint32_t* s = w + (base >> 1);
      uint32_t w0 = s[0], w1 = s[1];
      o.x = (uint16_t)(w0 & 0xffffu); o.y = (uint16_t)(w0 >> 16);
      o.z = (uint16_t)(w1 & 0xffffu); o.w = (uint16_t)(w1 >> 16);
    }
    *(ushort4*)((uint16_t*)(ws + offs[t]) + base) = o;
  } else {
    float* dst = ws + offs[t];
    if (sf) {
      *(float4*)(dst + base) = *(const float4*)((const float*)w + base);
    } else {
      const uint32_t* s = w + (base >> 1);
      uint32_t w0 = s[0], w1 = s[1];
      float4 o;
      o.x = __uint_as_float((w0 & 0xffffu) << 16);
      o.y = __uint_as_float(w0 & 0xffff0000u);
      o.z = __uint_as_float((w1 & 0xffffu) << 16);
      o.w = __uint_as_float(w1 & 0xffff0000u);
      *(float4*)(dst + base) = o;
    }
  }
}

// ---------------- W2 = IPW(2320x512) @ CWT(192x512)^T -> bf16 [e][k'] ----------------
// 2-phase K staging. Plus blocks 111..120: bias2[e] = IPW.cb, and ZX cls rows.
__global__ __launch_bounds__(256) void k_w2(const uint16_t* __restrict__ IPW,
                                            const uint16_t* __restrict__ CWT,
                                            const float* __restrict__ cb,
                                            const float* __restrict__ cls,
                                            uint16_t* __restrict__ W2,
                                            float* __restrict__ bias2,
                                            uint16_t* __restrict__ ZX) {
  int bx = blockIdx.x;
  int tid = threadIdx.x;

  if (bx >= 111) {                                  // bias2 + cls rows
    __shared__ float scb[512];
    __shared__ float scl[512];
    for (int i = tid; i < 512; i += 256) {
      scb[i] = cb[i];
      scl[i] = bf2f((uint16_t)f2bs(cls[i]));        // cls via bf16 (match old H path)
    }
    __syncthreads();
    int e = (bx - 111) * 232 + tid;
    if (tid < 232 && e < 2320) {
      float sb = 0.f, sc = 0.f;
      for (int d8 = 0; d8 < 512; d8 += 8) {
        ushortx8 v = *(const ushortx8*)(IPW + (long)e * 512 + d8);
#pragma unroll
        for (int j = 0; j < 8; ++j) {
          float wv = bf2f(v[j]);
          sb = fmaf(wv, scb[d8 + j], sb);
          sc = fmaf(wv, scl[d8 + j], sc);
        }
      }
      bias2[e] = sb;
      uint16_t cz = (uint16_t)f2bs(sc);
      ZX[(long)1024 * EPROJ + e] = cz;              // b=0 cls row
      ZX[(long)2049 * EPROJ + e] = cz;              // b=1 cls row (same value)
    }
    return;
  }

  int bm = bx / 3, bn = bx % 3;                     // 37 x 3 tiles of 64x64
  __shared__ __align__(16) short sA[64 * 264];
  __shared__ __align__(16) short sB[64 * 264];
  int lane = tid & 63, w = tid >> 6, lm = lane & 15, q = lane >> 4;

  floatx4 acc[4] = {};
  for (int ph = 0; ph < 2; ++ph) {                  // K = 2 x 256
    int d0 = ph * 256;
#pragma unroll
    for (int it = 0; it < 8; ++it) {
      int li = it * 256 + tid;                      // 0..2047
      int row = li >> 5, col = (li & 31) * 8;
      int ge = bm * 64 + row;
      ushortx8 av = {0,0,0,0,0,0,0,0};
      if (ge < 2320) av = *(const ushortx8*)(IPW + (long)ge * 512 + d0 + col);
      *(ushortx8*)&sA[row * 264 + col] = av;
      ushortx8 bv = *(const ushortx8*)(CWT + (long)(bn * 64 + row) * 512 + d0 + col);
      *(ushortx8*)&sB[row * 264 + col] = bv;
    }
    __syncthreads();
#pragma unroll
    for (int kk = 0; kk < 8; ++kk) {
      short8 a = *(const short8*)&sA[(w * 16 + lm) * 264 + kk * 32 + q * 8];
#pragma unroll
      for (int ct = 0; ct < 4; ++ct) {
        short8 b = *(const short8*)&sB[(ct * 16 + lm) * 264 + kk * 32 + q * 8];
        acc[ct] = __builtin_amdgcn_mfma_f32_16x16x32_bf16(a, b, acc[ct], 0, 0, 0);
      }
    }
    __syncthreads();
  }
#pragma unroll
  for (int reg = 0; reg < 4; ++reg) {
    int e = bm * 64 + w * 16 + q * 4 + reg;
    if (e < 2320) {
#pragma unroll
      for (int ct = 0; ct < 4; ++ct)
        W2[(long)e * 192 + bn * 64 + ct * 16 + lm] = (uint16_t)f2bs(acc[ct][reg]);
    }
  }
}

// ---------------- in_proj (fused with conv-embed): ZX = X3 @ W2^T + bias2 ----------------
__global__ __launch_bounds__(256) void k_ipgemm(const uint16_t* __restrict__ X3,
                                                const uint16_t* __restrict__ W2,
                                                const float* __restrict__ bias2,
                                                const uint8_t* __restrict__ keep,
                                                uint16_t* __restrict__ ZX) {
  __shared__ __align__(16) short sA[64 * 200];
  __shared__ __align__(16) short sB[64 * 200];
  __shared__ uint8_t skp[64];
  int tid = threadIdx.x;
  int lane = tid & 63, w = tid >> 6, lm = lane & 15, q = lane >> 4;
  int bm = blockIdx.y * 64, bn = blockIdx.x * 64;

  if (tid < 64) {
    int rr = bm + tid;
    skp[tid] = keep[(rr >> 10) * LTOK + (rr & 1023)];
  }
#pragma unroll
  for (int it = 0; it < 6; ++it) {
    int li = it * 256 + tid;                        // 0..1535
    int row = li / 24, col = (li % 24) * 8;
    ushortx8 av = *(const ushortx8*)(X3 + (long)(bm + row) * 192 + col);
    *(ushortx8*)&sA[row * 200 + col] = av;
    int gn = bn + row;
    ushortx8 bv = {0,0,0,0,0,0,0,0};
    if (gn < 2320) bv = *(const ushortx8*)(W2 + (long)gn * 192 + col);
    *(ushortx8*)&sB[row * 200 + col] = bv;
  }
  __syncthreads();

  floatx4 acc[4] = {};
#pragma unroll
  for (int kb = 0; kb < 6; ++kb) {
    short8 a = *(const short8*)&sA[(w * 16 + lm) * 200 + kb * 32 + q * 8];
#pragma unroll
    for (int ct = 0; ct < 4; ++ct) {
      short8 b = *(const short8*)&sB[(ct * 16 + lm) * 200 + kb * 32 + q * 8];
      acc[ct] = __builtin_amdgcn_mfma_f32_16x16x32_bf16(a, b, acc[ct], 0, 0, 0);
    }
  }
#pragma unroll
  for (int reg = 0; reg < 4; ++reg) {
    int r = bm + w * 16 + q * 4 + reg;              // body index 0..2047
    long crow = (long)((r >> 10) * LTOK + (r & 1023));   // cls-gap remap
    int kp = skp[r - bm];
#pragma unroll
    for (int ct = 0; ct < 4; ++ct) {
      int e = bn + ct * 16 + lm;
      if (e < 2320 && (e >= DIN || kp))
        ZX[crow * EPROJ + e] = (uint16_t)f2bs(acc[ct][reg] + bias2[e]);
    }
  }
}

// ---------------- depthwise causal conv(4) + silu (+ fused dt/lga), 4 rows/block ----------------
__global__ __launch_bounds__(256) void k_conv1d(const uint16_t* __restrict__ zx,
                                                const float* __restrict__ w,
                                                const float* __restrict__ bias,
                                                uint16_t* __restrict__ xbc,
                                                const float* __restrict__ dtb,
                                                const float* __restrict__ alog,
                                                float* __restrict__ dt,
                                                float* __restrict__ lga) {
  int g = blockIdx.x;
  int tid = threadIdx.x;
  if (g >= 514) {                        // fused dt/lga: blocks 514..642
    int idx = (g - 514) * 256 + tid;
    if (idx < NROWS * NHEAD) {
      int rr = idx >> 4, h = idx & 15;
      float xv = bf2f(zx[(long)rr * EPROJ + (EPROJ - NHEAD) + h]) + dtb[h];
      float dtv = (xv > 20.f) ? xv : log1pf(expf(xv));
      dt[idx] = dtv;
      lga[idx] = dtv * (-expf(alog[h]));
    }
    return;
  }
  // bijective XCD swizzle for 514 groups (8 XCDs: q=64, rem=2)
  {
    int xcd = g & 7, slot = g >> 3;
    g = (xcd < 2) ? xcd * 65 + slot : 130 + (xcd - 2) * 64 + slot;
  }
  int b = g / 257, gi = g % 257;
  int t0 = gi * 4;
  int nr = (t0 == 1024) ? 1 : 4;
  const uint16_t* zrow = zx + (long)b * LTOK * EPROJ + DIN;
  for (int c4 = tid * 4; c4 < CDIM; c4 += 1024) {
    float4 bi = *(const float4*)(bias + c4);
    float4 w0 = *(const float4*)(w + (c4 + 0) * 4);
    float4 w1 = *(const float4*)(w + (c4 + 1) * 4);
    float4 w2 = *(const float4*)(w + (c4 + 2) * 4);
    float4 w3 = *(const float4*)(w + (c4 + 3) * 4);
    float wr[4][4] = {{w0.x, w0.y, w0.z, w0.w}, {w1.x, w1.y, w1.z, w1.w},
                      {w2.x, w2.y, w2.z, w2.w}, {w3.x, w3.y, w3.z, w3.w}};
    float acc[4][4];                     // [row][chan]
#pragma unroll
    for (int ri = 0; ri < 4; ++ri) {
      acc[ri][0] = bi.x; acc[ri][1] = bi.y; acc[ri][2] = bi.z; acc[ri][3] = bi.w;
    }
#pragma unroll
    for (int dtt = -3; dtt <= 3; ++dtt) {
      int tt = t0 + dtt;
      if (tt < 0 || tt > 1024) continue;
      ushort4 xv = *(const ushort4*)(zrow + (long)tt * EPROJ + c4);
      float x0 = bf2f(xv.x), x1 = bf2f(xv.y), x2 = bf2f(xv.z), x3 = bf2f(xv.w);
#pragma unroll
      for (int ri = 0; ri < 4; ++ri) {
        int k = dtt - ri + 3;            // tap index for output row t0+ri
        if (k >= 0 && k <= 3) {
          acc[ri][0] = fmaf(wr[0][k], x0, acc[ri][0]);
          acc[ri][1] = fmaf(wr[1][k], x1, acc[ri][1]);
          acc[ri][2] = fmaf(wr[2][k], x2, acc[ri][2]);
          acc[ri][3] = fmaf(wr[3][k], x3, acc[ri][3]);
        }
      }
    }
#pragma unroll
    for (int ri = 0; ri < 4; ++ri) {
      if (ri < nr) {
        long r = (long)b * LTOK + t0 + ri;
        ushort4 o;
        o.x = (uint16_t)f2bs(acc[ri][0] / (1.f + expf(-acc[ri][0])));
        o.y = (uint16_t)f2bs(acc[ri][1] / (1.f + expf(-acc[ri][1])));
        o.z = (uint16_t)f2bs(acc[ri][2] / (1.f + expf(-acc[ri][2])));
        o.w = (uint16_t)f2bs(acc[ri][3] / (1.f + expf(-acc[ri][3])));
        *(ushort4*)(xbc + r * CDIM + c4) = o;
      }
    }
  }
}

// ---------------- SSD phase 1: chunk states only (SL bf16, CLA) ----------------
__global__ __launch_bounds__(256) void k_ssd1(const uint16_t* __restrict__ xbc,
                                              const float* __restrict__ dt,
                                              const float* __restrict__ lga,
                                              uint16_t* __restrict__ SL,
                                              float* __restrict__ CLA) {
  int blk = blockIdx.x;
  int c = blk % NCH;
  int hh = blk / NCH;            // h + 16*b
  int h = hh & 15, b = hh >> 4;
  int tid = threadIdx.x;
  int lane = tid & 63, w = tid >> 6;
  int lm = lane & 15, q = lane >> 4;

  __shared__ __align__(16) short sBT[128 * 72];
  __shared__ __align__(16) short sXT[64 * 72];
  __shared__ float wwv[64];

  int t0 = c * QC;
  const uint16_t* base = xbc + (long)b * LTOK * CDIM;

  if (tid < 64) {                // wave 0: loads + parallel inclusive scan
    int t = t0 + tid;
    float dtv = (t < LTOK) ? dt[((long)(b * LTOK + t)) * NHEAD + h] : 0.f;
    float v   = (t < LTOK) ? lga[((long)(b * LTOK + t)) * NHEAD + h] : 0.f;
#pragma unroll
    for (int off = 1; off < 64; off <<= 1) {
      float u = __shfl_up(v, off, 64);
      if (lane >= off) v += u;
    }
    float clEnd = __shfl(v, 63, 64);
    wwv[tid] = __expf(clEnd - v) * dtv;
    CLA[(long)blk * 64 + tid] = v;
  }
  __syncthreads();

#pragma unroll
  for (int k = 0; k < 8; ++k) {
    int e4 = (tid + k * 256) * 4;
    int row = e4 >> 7, col = e4 & 127;
    int t = t0 + row;
    ushort4 bv = {0,0,0,0};
    if (t < LTOK) bv = *(const ushort4*)(base + (long)t * CDIM + DIN + col);
    float wv = wwv[row];
    sBT[(col  )*72+row]=f2bs(bf2f(bv.x)*wv); sBT[(col+1)*72+row]=f2bs(bf2f(bv.y)*wv);
    sBT[(col+2)*72+row]=f2bs(bf2f(bv.z)*wv); sBT[(col+3)*72+row]=f2bs(bf2f(bv.w)*wv);
  }
#pragma unroll
  for (int k = 0; k < 4; ++k) {
    int e4 = (tid + k * 256) * 4;
    int row = e4 >> 6, col = e4 & 63;
    int t = t0 + row;
    ushort4 xv = {0,0,0,0};
    if (t < LTOK) xv = *(const ushort4*)(base + (long)t * CDIM + h * 64 + col);
    sXT[(col  )*72+row]=(short)xv.x; sXT[(col+1)*72+row]=(short)xv.y;
    sXT[(col+2)*72+row]=(short)xv.z; sXT[(col+3)*72+row]=(short)xv.w;
  }
  __syncthreads();

  floatx4 s[2][4] = {};
#pragma unroll
  for (int kb = 0; kb < 2; ++kb) {
    short8 bfr[4];
#pragma unroll
    for (int ct = 0; ct < 4; ++ct)
      bfr[ct] = *(const short8*)&sXT[(ct*16 + lm)*72 + kb*32 + q*8];
#pragma unroll
    for (int nt = 0; nt < 2; ++nt) {
      short8 a = *(const short8*)&sBT[((w*2+nt)*16 + lm)*72 + kb*32 + q*8];
#pragma unroll
      for (int ct = 0; ct < 4; ++ct)
        s[nt][ct] = __builtin_amdgcn_mfma_f32_16x16x32_bf16(a, bfr[ct], s[nt][ct], 0, 0, 0);
    }
  }
  uint16_t* slp = SL + (long)blk * 8192;
#pragma unroll
  for (int nt = 0; nt < 2; ++nt)
#pragma unroll
    for (int ct = 0; ct < 4; ++ct)
#pragma unroll
      for (int reg = 0; reg < 4; ++reg) {
        int n = (w*2+nt)*16 + q*4 + reg;
        int p = ct*16 + lm;
        slp[n*64 + p] = (uint16_t)f2bs(s[nt][ct][reg]);
      }
}

// ---------------- SSD phase 2a: prefix scan over chunks (bf16 in, f32 scan, bf16 out) ----------------
__global__ __launch_bounds__(256) void k_comb(const uint16_t* __restrict__ SL,
                                              const float* __restrict__ CLA,
                                              uint16_t* __restrict__ SL2) {
  int bx = blockIdx.x;
  int piece = bx & 15;
  int hh = bx >> 4;
  int off = piece * 512 + threadIdx.x * 2;
  long cb0 = (long)hh * NCH;
  float P[NCH];
  float2 tmp[NCH];
#pragma unroll
  for (int c = 0; c < NCH; ++c) {
    P[c] = __expf(CLA[(cb0 + c) * 64 + 63]);
    uint32_t pk = *(const uint32_t*)(SL + (cb0 + c) * 8192 + off);
    tmp[c].x = bf2f((uint16_t)(pk & 0xffffu));
    tmp[c].y = bf2f((uint16_t)(pk >> 16));
  }
  float2 s = make_float2(0.f, 0.f);
#pragma unroll
  for (int c = 0; c < NCH; ++c) {
    uint32_t packed = (uint32_t)(uint16_t)f2bs(s.x) | ((uint32_t)(uint16_t)f2bs(s.y) << 16);
    *(uint32_t*)(SL2 + (cb0 + c) * 8192 + off) = packed;
    s.x = fmaf(P[c], s.x, tmp[c].x);
    s.y = fmaf(P[c], s.y, tmp[c].y);
  }
}

// ---------------- SSD phase 2b: FULL Y, B/C fragments direct from global ----------------
__global__ __launch_bounds__(256) void k_ssd3(const uint16_t* __restrict__ xbc,
                                              const float* __restrict__ dt,
                                              const uint16_t* __restrict__ SL2,
                                              const float* __restrict__ CLA,
                                              const uint8_t* __restrict__ keepf,
                                              float* __restrict__ Y) {
  int blk = blockIdx.x;
  int c = blk % NCH;
  int hh = blk / NCH;
  int h = hh & 15, b = hh >> 4;
  int tid = threadIdx.x;
  int lane = tid & 63, w = tid >> 6;
  int lm = lane & 15, q = lane >> 4;

  __shared__ __align__(16) short sST[64 * 136];   // S^T[p][n]
  __shared__ __align__(16) short sXT[64 * 72];    // X^T[p][t]
  __shared__ __align__(16) short sM[64 * 72];     // M[tl][tp]
  __shared__ float dtw[64], clA[64], evec[64];
  __shared__ uint8_t kf[64];

  int t0 = c * QC;
  const uint16_t* base = xbc + (long)b * LTOK * CDIM;
  const uint16_t* slp = SL2 + (long)blk * 8192;

  if (tid < 64) {
    int t = t0 + tid;
    dtw[tid] = (t < LTOK) ? dt[((long)(b * LTOK + t)) * NHEAD + h] : 0.f;
    float v = CLA[(long)blk * 64 + tid];
    clA[tid] = v;
    evec[tid] = __expf(v);
    kf[tid] = (t < LTOK) ? keepf[b * LTOK + t] : 0;
  }

#pragma unroll
  for (int k = 0; k < 4; ++k) {
    int e4 = (tid + k * 256) * 4;
    int row = e4 >> 6, col = e4 & 63;
    int t = t0 + row;
    ushort4 xv = {0,0,0,0};
    if (t < LTOK) xv = *(const ushort4*)(base + (long)t * CDIM + h * 64 + col);
    sXT[(col  )*72+row]=(short)xv.x; sXT[(col+1)*72+row]=(short)xv.y;
    sXT[(col+2)*72+row]=(short)xv.z; sXT[(col+3)*72+row]=(short)xv.w;
  }
#pragma unroll
  for (int k = 0; k < 8; ++k) {
    int e4 = (tid + k * 256) * 4;
    int n = e4 >> 6, p = e4 & 63;
    ushort4 sv = *(const ushort4*)(slp + n * 64 + p);
    sST[(p  )*136+n]=(short)sv.x; sST[(p+1)*136+n]=(short)sv.y;
    sST[(p+2)*136+n]=(short)sv.z; sST[(p+3)*136+n]=(short)sv.w;
  }
  __syncthreads();     // staging + wave0 init visible

  // C fragments (registers) — shared between G and y2 matmuls; direct global (L2-hot)
  short8 cfr[4];
  int tA = t0 + w*16 + lm;
  bool tAok = tA < LTOK;
#pragma unroll
  for (int kb = 0; kb < 4; ++kb) {
    short8 z = {0,0,0,0,0,0,0,0};
    cfr[kb] = tAok ? *(const short8*)(base + (long)tA * CDIM + DIN + DST + kb*32 + q*8) : z;
  }

  // G = C . B^T : B fragments direct from global
  floatx4 g[4] = {};
#pragma unroll
  for (int kb = 0; kb < 4; ++kb) {
#pragma unroll
    for (int ct = 0; ct < 4; ++ct) {
      int tB = t0 + ct*16 + lm;
      short8 z = {0,0,0,0,0,0,0,0};
      short8 bb = (tB < LTOK) ? *(const short8*)(base + (long)tB * CDIM + DIN + kb*32 + q*8) : z;
      g[ct] = __builtin_amdgcn_mfma_f32_16x16x32_bf16(cfr[kb], bb, g[ct], 0, 0, 0);
    }
  }
  // M[tl][tp] = tril(G) * exp(clA[tl]-clA[tp]) * dt[tp]
#pragma unroll
  for (int ct = 0; ct < 4; ++ct) {
    int tp = ct*16 + lm;
#pragma unroll
    for (int reg = 0; reg < 4; ++reg) {
      int tl = w*16 + q*4 + reg;
      float m = 0.f;
      if (tp <= tl) m = g[ct][reg] * __expf(clA[tl] - clA[tp]) * dtw[tp];
      sM[tl*72 + tp] = f2bs(m);
    }
  }
  // cross-chunk: y2 = C . S_start^T (overlaps the sM barrier)
  floatx4 y2[4] = {};
#pragma unroll
  for (int kb = 0; kb < 4; ++kb) {
#pragma unroll
    for (int ct = 0; ct < 4; ++ct) {
      short8 bb = *(const short8*)&sST[(ct*16 + lm)*136 + kb*32 + q*8];
      y2[ct] = __builtin_amdgcn_mfma_f32_16x16x32_bf16(cfr[kb], bb, y2[ct], 0, 0, 0);
    }
  }
  __syncthreads();     // sM visible
  // within-chunk: y1 = M . X
  floatx4 y1[4] = {};
#pragma unroll
  for (int kb = 0; kb < 2; ++kb) {
    short8 a = *(const short8*)&sM[(w*16 + lm)*72 + kb*32 + q*8];
#pragma unroll
    for (int ct = 0; ct < 4; ++ct) {
      short8 bb = *(const short8*)&sXT[(ct*16 + lm)*72 + kb*32 + q*8];
      y1[ct] = __builtin_amdgcn_mfma_f32_16x16x32_bf16(a, bb, y1[ct], 0, 0, 0);
    }
  }
#pragma unroll
  for (int reg = 0; reg < 4; ++reg) {
    int tl = w*16 + q*4 + reg;
    int t = t0 + tl;
    if (t < LTOK && kf[tl]) {
      float ev = evec[tl];
#pragma unroll
      for (int ct = 0; ct < 4; ++ct) {
        int p = ct*16 + lm;
        Y[((long)(b * LTOK + t)) * DIN + h * 64 + p] = y1[ct][reg] + ev * y2[ct][reg];
      }
    }
  }
}

// ---------------- gathered rows only: y(+D*x) + gate silu(z) + RMSNorm -> bf16 ----------------
__global__ __launch_bounds__(256) void k_gaterms(const float* __restrict__ Y,
                                                 const uint16_t* __restrict__ xbc,
                                                 const uint16_t* __restrict__ zx,
                                                 const float* __restrict__ Dv,
                                                 const float* __restrict__ rmsw,
                                                 const int* __restrict__ ridx,
                                                 uint16_t* __restrict__ G) {
  int rr = blockIdx.x;
  long r = ridx[rr];
  int tid = threadIdx.x;
  int e = tid * 4;
  int h = tid >> 4;
  float4 a = *(const float4*)(Y + r * DIN + e);
  const ushort4 xu = *(const ushort4*)(xbc + r * CDIM + e);
  const ushort4 zu = *(const ushort4*)(zx + r * EPROJ + e);
  float Dh = Dv[h];
  float y0 = a.x + Dh * bf2f(xu.x), y1 = a.y + Dh * bf2f(xu.y);
  float y2 = a.z + Dh * bf2f(xu.z), y3 = a.w + Dh * bf2f(xu.w);
  float z0 = bf2f(zu.x), z1 = bf2f(zu.y), z2 = bf2f(zu.z), z3 = bf2f(zu.w);
  float g0 = y0 * (z0 / (1.f + expf(-z0)));
  float g1 = y1 * (z1 / (1.f + expf(-z1)));
  float g2 = y2 * (z2 / (1.f + expf(-z2)));
  float g3 = y3 * (z3 / (1.f + expf(-z3)));
  __shared__ float red[256];
  red[tid] = g0*g0 + g1*g1 + g2*g2 + g3*g3;
  __syncthreads();
  for (int st = 128; st; st >>= 1) {
    if (tid < st) red[tid] += red[tid + st];
    __syncthreads();
  }
  float scale = rsqrtf(red[0] * (1.0f / 1024.0f) + 1e-5f);
  float4 rw = *(const float4*)(rmsw + e);
  ushort4 o;
  o.x = (uint16_t)f2bs(g0 * scale * rw.x);
  o.y = (uint16_t)f2bs(g1 * scale * rw.y);
  o.z = (uint16_t)f2bs(g2 * scale * rw.z);
  o.w = (uint16_t)f2bs(g3 * scale * rw.w);
  *(ushort4*)(G + (long)rr * DIN + e) = o;
}

// ---------------- out_proj GEMM, one-shot K-slice, no atomics ----------------
__global__ __launch_bounds__(256) void k_ogemm(const uint16_t* __restrict__ A,
                                               const uint16_t* __restrict__ Bw,
                                               float* __restrict__ OUTP) {
  __shared__ __align__(16) short sA[64 * 264];
  __shared__ __align__(16) short sB[64 * 264];
  int tid = threadIdx.x;
  int lane = tid & 63, w = tid >> 6;
  int lm = lane & 15, q = lane >> 4;
  int bm = blockIdx.y * 64, bn = blockIdx.x * 64;
  int kbase = blockIdx.z * 256;

#pragma unroll
  for (int it = 0; it < 8; ++it) {
    int li = it * 256 + tid;              // 0..2047
    int row = li >> 5, col = (li & 31) * 8;
    int gm = bm + row;
    ushortx8 av = {0,0,0,0,0,0,0,0};
    if (gm < 514) av = *(const ushortx8*)(A + (long)gm * 1024 + kbase + col);
    *(ushortx8*)&sA[row * 264 + col] = av;
    ushortx8 bv = *(const ushortx8*)(Bw + (long)(bn + row) * 1024 + kbase + col);
    *(ushortx8*)&sB[row * 264 + col] = bv;
  }
  __syncthreads();

  floatx4 acc[4] = {};
#pragma unroll
  for (int kb = 0; kb < 8; ++kb) {
    short8 a = *(const short8*)&sA[(w * 16 + lm) * 264 + kb * 32 + q * 8];
#pragma unroll
    for (int ct = 0; ct < 4; ++ct) {
      short8 b = *(const short8*)&sB[(ct * 16 + lm) * 264 + kb * 32 + q * 8];
      acc[ct] = __builtin_amdgcn_mfma_f32_16x16x32_bf16(a, b, acc[ct], 0, 0, 0);
    }
  }
  float* op = OUTP + (long)blockIdx.z * 263168;
#pragma unroll
  for (int reg = 0; reg < 4; ++reg) {
    int r = bm + w * 16 + q * 4 + reg;
    if (r < 514) {
#pragma unroll
      for (int ct = 0; ct < 4; ++ct)
        op[(long)r * 512 + bn + ct * 16 + lm] = acc[ct][reg];
    }
  }
}

// ---------------- final LayerNorm (sums 4 out_proj partials) -> f32 out ----------------
__global__ __launch_bounds__(256) void k_ln(const float* __restrict__ outp,
                                            const float* __restrict__ lng,
                                            const float* __restrict__ lnb,
                                            float* __restrict__ out) {
  int r = blockIdx.x;
  int tid = threadIdx.x;
  long e = (long)r * DM + tid * 2;
  float2 v0 = *(const float2*)(outp + e);
  float2 v1 = *(const float2*)(outp + 263168 + e);
  float2 v2 = *(const float2*)(outp + 2 * 263168 + e);
  float2 v3 = *(const float2*)(outp + 3 * 263168 + e);
  float2 v;
  v.x = ((v0.x + v1.x) + v2.x) + v3.x;
  v.y = ((v0.y + v1.y) + v2.y) + v3.y;
  __shared__ float red[256];
  red[tid] = v.x + v.y;
  __syncthreads();
  for (int st = 128; st; st >>= 1) { if (tid < st) red[tid] += red[tid + st]; __syncthreads(); }
  float mu = red[0] * (1.0f / 512.0f);
  __syncthreads();
  float dx = v.x - mu, dy = v.y - mu;
  red[tid] = dx * dx + dy * dy;
  __syncthreads();
  for (int st = 128; st; st >>= 1) { if (tid < st) red[tid] += red[tid + st]; __syncthreads(); }
  float sc = rsqrtf(red[0] * (1.0f / 512.0f) + 1e-5f);
  int c = tid * 2;
  out[(long)r * DM + c]     = dx * sc * lng[c] + lnb[c];
  out[(long)r * DM + c + 1] = dy * sc * lng[c + 1] + lnb[c + 1];
}

// ---------------- launch ----------------
extern "C" void kernel_launch(void* const* d_in, const int* in_sizes, int n_in,
                              void* d_out, int out_size, void* d_ws, size_t ws_size,
                              hipStream_t stream) {
  float* ws = (float*)d_ws;
  float* out = (float*)d_out;
  int* rowidx = (int*)(ws + O_RIDX);
  InPtrs ip;
  for (int i = 0; i < 14; ++i) ip.p[i] = d_in[i];

  // convert (+CWT reorder) + RNG/keep + vectorized im2col (k' layout)
  hipLaunchKernelGGL(k_convert, dim3(2071), dim3(256), 0, stream, ip, ws, out, rowidx);
  // W2 = IPW @ CW (fused conv-embed x in_proj weights, k' order) + bias2 + cls ZX rows
  hipLaunchKernelGGL(k_w2, dim3(121), dim3(256), 0, stream,
                     (const uint16_t*)(ws + O_IPW), (const uint16_t*)(ws + O_CWT),
                     ws + O_CB, ws + O_CLS,
                     (uint16_t*)(ws + O_W2), ws + O_BIAS2, (uint16_t*)(ws + O_ZX));
  // in_proj fused GEMM: ZX body = X3 @ W2^T + bias2 (one-shot K=192, keep-masked z)
  hipLaunchKernelGGL(k_ipgemm, dim3(37, 32), dim3(256), 0, stream,
                     (const uint16_t*)(ws + O_X3), (const uint16_t*)(ws + O_W2),
                     ws + O_BIAS2, (const uint8_t*)(ws + O_KEEP),
                     (uint16_t*)(ws + O_ZX));
  // conv + silu (bf16 zx -> bf16 xbc), 4 rows/block + dt/lga blocks
  hipLaunchKernelGGL(k_conv1d, dim3(643), dim3(256), 0, stream,
                     (const uint16_t*)(ws + O_ZX), ws + O_C1W, ws + O_C1B,
                     (uint16_t*)(ws + O_XBC),
                     ws + O_DTB, ws + O_ALOG, ws + O_DT, ws + O_LGA);
  // phase 1: chunk states (bf16) + cumsum
  hipLaunchKernelGGL(k_ssd1, dim3(32 * NCH), dim3(256), 0, stream,
                     (const uint16_t*)(ws + O_XBC), ws + O_DT, ws + O_LGA,
                     (uint16_t*)(ws + O_SL), ws + O_CLA);
  // phase 2a: prefix states (bf16 in/out, f32 scan)
  hipLaunchKernelGGL(k_comb, dim3(512), dim3(256), 0, stream,
                     (const uint16_t*)(ws + O_SL), ws + O_CLA, (uint16_t*)(ws + O_SL2));
  // phase 2b: full Y (within + cross chunk), keep-masked single write
  hipLaunchKernelGGL(k_ssd3, dim3(32 * NCH), dim3(256), 0, stream,
                     (const uint16_t*)(ws + O_XBC), ws + O_DT,
                     (const uint16_t*)(ws + O_SL2), ws + O_CLA,
                     (const uint8_t*)(ws + O_KEEP), ws + O_Y);
  // gather(514) + gate + RMS -> bf16 into dead X3 buffer
  hipLaunchKernelGGL(k_gaterms, dim3(514), dim3(256), 0, stream,
                     ws + O_Y, (const uint16_t*)(ws + O_XBC),
                     (const uint16_t*)(ws + O_ZX), ws + O_DV, ws + O_RMSW,
                     (const int*)rowidx, (uint16_t*)(ws + O_X3));
  // out_proj GEMM: one-shot K-slices, no atomics, 288 blocks -> 4 f32 partials
  hipLaunchKernelGGL(k_ogemm, dim3(8, 9, 4), dim3(256), 0, stream,
                     (const uint16_t*)(ws + O_X3), (const uint16_t*)(ws + O_OPW),
                     ws + O_OUTP);
  // LN sums the 4 partials inline
  hipLaunchKernelGGL(k_ln, dim3(514), dim3(256), 0, stream,
                     ws + O_OUTP, ws + O_LNG, ws + O_LNB, out);
}

// Round 12
// 179.122 us; speedup vs baseline: 1.0298x; 1.0298x over previous
//
#include <hip/hip_runtime.h>
#include <hip/hip_bf16.h>
#include <stdint.h>

// ---------------- problem constants ----------------
#define LTOK  1025      // 1024 body + 1 cls
#define NROWS 2050      // B * LTOK
#define DM    512
#define DIN   1024
#define DST   128
#define NHEAD 16
#define HDIM  64
#define CDIM  1280      // DIN + 2*DST
#define EPROJ 2320      // 2*DIN + 2*DST + NHEAD
#define QC    64        // SSD chunk length
#define NCH   17        // ceil(1025/64)

// ---------------- workspace layout (float offsets), ws = 256 MiB ----------------
#define O_RIDX   0          // int32 x 514 (reserve 1024)
#define O_CB     1024
#define O_CLS    1536
#define O_C1B    2048
#define O_DTB    3328
#define O_ALOG   3344
#define O_DV     3360
#define O_RMSW   3376
#define O_LNG    4400
#define O_LNB    4912
#define O_CW     5440       // (dead)
#define O_IPW    103744     // bf16 (ushort) 2320x512
#define O_OPW    1291584    // bf16 (ushort)
#define O_C1W    1815872
#define O_CX     1820992    // (dead)
#define O_ZX     1952064    // bf16 (ushort)
#define O_XBC    6708064    // bf16 (ushort)
#define O_DT     9332064
#define O_LGA    9364864    // log(dA) = dt * (-exp(A_log))
#define O_Y      9397664    // f32
#define O_X3     10447264   // bf16 (ushort); im2col A (k' layout), later gated bf16 G
#define O_OUTG   11496864   // (dead)
#define O_SL     11760032   // chunk states BF16 (ushort): 32*17*8192 ushorts
#define O_CLA    16216480   // within-chunk cumsum logdA: 32*17*64
#define O_SL2    16251296   // bf16 prefix states: 32*17*8192 ushorts
#define O_KEEP   18479520   // uint8 keep flags x 2050
#define O_OUTP   18480128   // f32 out_proj partials: 4 x 514*512
#define O_CWT    19532800   // bf16 CW^T reordered (192x512): row k' = tap*64 + i
#define O_W2     19581952   // bf16 W2 (2320x192, k' order) = 445440 ushorts
#define O_BIAS2  19804672   // f32 bias2 (2320)

// ---------------- output layout (FLOAT32 elements) ----------------
#define OO_MASK 263168
#define OO_IDR  265216
#define OO_IDK  267264

typedef __attribute__((ext_vector_type(8))) short short8;
typedef __attribute__((ext_vector_type(8))) unsigned short ushortx8;
typedef __attribute__((ext_vector_type(4))) float floatx4;

__device__ __forceinline__ short f2bs(float f) {
  union { float f; uint32_t u; } v; v.f = f;
  uint32_t r = (v.u + 0x7FFFu + ((v.u >> 16) & 1u)) >> 16;
  return (short)r;
}
__device__ __forceinline__ float bf2f(uint16_t u) {
  return __uint_as_float(((uint32_t)u) << 16);
}

struct InPtrs { const void* p[14]; };

// ---------------- threefry2x32 (JAX-compatible) ----------------
__device__ __forceinline__ uint32_t rotl32(uint32_t v, int d) {
  return (v << d) | (v >> (32 - d));
}
__device__ void threefry2x32(uint32_t k0, uint32_t k1, uint32_t c0, uint32_t c1,
                             uint32_t& o0, uint32_t& o1) {
  uint32_t ks0 = k0, ks1 = k1, ks2 = 0x1BD11BDAu ^ k0 ^ k1;
  uint32_t x0 = c0 + ks0, x1 = c1 + ks1;
#define TF_R4(a,b,c,d) \
  x0 += x1; x1 = rotl32(x1,a); x1 ^= x0; \
  x0 += x1; x1 = rotl32(x1,b); x1 ^= x0; \
  x0 += x1; x1 = rotl32(x1,c); x1 ^= x0; \
  x0 += x1; x1 = rotl32(x1,d); x1 ^= x0;
  TF_R4(13,15,26,6)  x0 += ks1; x1 += ks2 + 1u;
  TF_R4(17,29,16,24) x0 += ks2; x1 += ks0 + 2u;
  TF_R4(13,15,26,6)  x0 += ks0; x1 += ks1 + 3u;
  TF_R4(17,29,16,24) x0 += ks1; x1 += ks2 + 4u;
  TF_R4(13,15,26,6)  x0 += ks2; x1 += ks0 + 5u;
#undef TF_R4
  o0 = x0; o1 = x1;
}

// ---------------- input dtype detect ----------------
__device__ int detect_is_f32(const uint32_t* w, int nelem) {
  int nw = nelem / 2; if (nw > 16) nw = 16;
  int insane = 0, lozero = 0, anynz = 0;
  for (int i = 0; i < nw; ++i) {
    uint32_t word = w[i];
    if (word != 0u) anynz = 1;
    uint32_t lo = word & 0xffffu;
    if (lo == 0u) { lozero++; continue; }
    float v = __uint_as_float(lo << 16);
    float a = fabsf(v);
    if (!(a >= 1e-8f && a <= 1e4f)) insane++;
  }
  if (insane >= 2) return 1;
  if (lozero == nw && anynz) return 1;
  return 0;
}

// ---------------- convert + RNG/keep + im2col(vec,k'), flattened 1-D grid (2071 blocks) ----------------
// [0,256)       im2col vectorized: 8 rows/block, X3[r][k'] with k' = tap*64 + i
// [256,1416)    IPW convert (t=3), 1160 blocks
// [1416,1928)   OPW convert (t=10), 512 blocks
// [1928,2024)   CWT transpose-reorder (row k' = tap*64 + i), 96 blocks
// [2024,2056)   RNG/keep, 32 blocks
// [2056,2071)   15 small-tensor jobs
__global__ __launch_bounds__(256) void k_convert(InPtrs ptrs, float* ws,
                                                 float* out, int* rowidx) {
  static const int sizes[13] = {98304, 512, 512, 1187840, 5120, 1280,
                                16, 16, 16, 1024, 524288, 512, 512};
  static const int offs[13]  = {O_CW, O_CB, O_CLS, O_IPW, O_C1W, O_C1B,
                                O_DTB, O_ALOG, O_DV, O_RMSW, O_OPW, O_LNG, O_LNB};
  static const int isbf[13]  = {1,0,0,1,0,0,0,0,0,0,1,0,0};
  static const int smallT[15] = {1,2,4,4,4,4,4,5,5,6,7,8,9,11,12};
  static const int smallB[15] = {0,0,0,1,2,3,4,0,1,0,0,0,0,0,0};
  int bx = blockIdx.x;
  int tid = threadIdx.x;

  if (bx < 256) {                                   // im2col vectorized, k' layout
    const uint32_t* xp = (const uint32_t*)ptrs.p[0];
    __shared__ int xf;
    if (tid == 0) xf = detect_is_f32(xp, 131072);
    __syncthreads();
    if (tid < 192) {
      int r = bx * 8 + tid / 24;                    // 0..2047
      int seg = tid % 24;
      int kk = seg >> 3, i0 = (seg & 7) * 8;        // k' = kk*64 + i0
      int b = r >> 10, idx = r & 1023;
      int tt = idx + kk - 1;
      ushortx8 o = {0,0,0,0,0,0,0,0};
      if (tt >= 0 && tt < 1024) {
        long src = ((long)(b * 1024 + tt)) * 64 + i0;
        if (xf) {
          const float* xfp = (const float*)xp;
          float4 f0 = *(const float4*)(xfp + src);
          float4 f1 = *(const float4*)(xfp + src + 4);
          o[0] = (uint16_t)f2bs(f0.x); o[1] = (uint16_t)f2bs(f0.y);
          o[2] = (uint16_t)f2bs(f0.z); o[3] = (uint16_t)f2bs(f0.w);
          o[4] = (uint16_t)f2bs(f1.x); o[5] = (uint16_t)f2bs(f1.y);
          o[6] = (uint16_t)f2bs(f1.z); o[7] = (uint16_t)f2bs(f1.w);
        } else {
          o = *(const ushortx8*)((const uint16_t*)xp + src);
        }
      }
      *(ushortx8*)((uint16_t*)(ws + O_X3) + (long)r * 192 + kk * 64 + i0) = o;
    }
    return;
  }
  bx -= 256;

  int t, blk;
  if (bx < 1160) { t = 3; blk = bx; }
  else {
    bx -= 1160;
    if (bx < 512) { t = 10; blk = bx; }
    else {
      bx -= 512;
      if (bx < 96) {                                // CWT transpose-reorder (conv_emb_w)
        const uint32_t* w = (const uint32_t*)ptrs.p[1];
        __shared__ int sf;
        if (tid == 0) sf = detect_is_f32(w, 98304);
        __syncthreads();
        int base = (bx * 256 + tid) * 4;
        if (base >= 98304) return;
        uint16_t vv[4];
        if (sf) {
          const float4 f = *(const float4*)((const float*)w + base);
          vv[0] = (uint16_t)f2bs(f.x); vv[1] = (uint16_t)f2bs(f.y);
          vv[2] = (uint16_t)f2bs(f.z); vv[3] = (uint16_t)f2bs(f.w);
        } else {
          const uint32_t* s = w + (base >> 1);
          uint32_t w0 = s[0], w1 = s[1];
          vv[0] = (uint16_t)(w0 & 0xffffu); vv[1] = (uint16_t)(w0 >> 16);
          vv[2] = (uint16_t)(w1 & 0xffffu); vv[3] = (uint16_t)(w1 >> 16);
        }
        int o = base / 192, ik = base % 192;        // flat = o*192 + i*3 + tap
        uint16_t* cwt = (uint16_t*)(ws + O_CWT);
#pragma unroll
        for (int j = 0; j < 4; ++j) {
          int ikj = ik + j;
          int kp = (ikj % 3) * 64 + (ikj / 3);      // k' = tap*64 + i
          cwt[(long)kp * 512 + o] = vv[j];
        }
        return;
      }
      bx -= 96;
      if (bx < 32) {                                // RNG / keep / rowidx
        int seg = bx & 15, b = bx >> 4;
        uint8_t* keep = (uint8_t*)(ws + O_KEEP);
        __shared__ float vals[1024];
        uint32_t fk0, fk1;
        threefry2x32(0u, 0u, 0u, 1u, fk0, fk1);     // fold_in(key(0), 1)
#pragma unroll
        for (int k = 0; k < 4; ++k) {
          int i = tid + k * 256;
          uint32_t o0, o1;
          threefry2x32(fk0, fk1, 0u, (uint32_t)(b * 1024 + i), o0, o1);
          uint32_t bits = o0 ^ o1;
          vals[i] = __uint_as_float((bits >> 9) | 0x3f800000u) - 1.0f;
        }
        __syncthreads();
        int tg = seg * 64 + (tid >> 2);
        int qq = tid & 3;
        float v = vals[tg];
        int r = 0;
        int j0 = qq * 256;
        for (int it = 0; it < 256; ++it) {
          int j = j0 + ((it + qq * 8) & 255);
          float vj = vals[j];
          r += (vj < v || (vj == v && j < tg)) ? 1 : 0;
        }
        r += __shfl_xor(r, 1, 64);
        r += __shfl_xor(r, 2, 64);
        if (qq == 0) {
          out[OO_IDR + b * 1024 + tg] = (float)r;
          out[OO_MASK + b * 1024 + tg] = (r < 256) ? 0.0f : 1.0f;
          keep[b * LTOK + tg] = (r < 256) ? 1 : 0;
          if (r < 256) {
            out[OO_IDK + b * 256 + r] = (float)tg;
            rowidx[b * 257 + r] = b * LTOK + tg;
          }
          if (tg == 0) {
            rowidx[b * 257 + 256] = b * LTOK + 1024;
            keep[b * LTOK + 1024] = 1;
          }
        }
        return;
      }
      bx -= 32;
      if (bx >= 15) return;
      t = smallT[bx]; blk = smallB[bx];
    }
  }

  // generic conversion job (t, blk)
  int n = sizes[t];
  const uint32_t* w = (const uint32_t*)ptrs.p[t + 1];
  __shared__ int sf;
  if (tid == 0) sf = detect_is_f32(w, n);
  __syncthreads();
  int base = (blk * 256 + tid) * 4;
  if (base >= n) return;
  if (isbf[t]) {
    ushort4 o;
    if (sf) {
      const float4 vv = *(const float4*)((const float*)w + base);
      o.x = (uint16_t)f2bs(vv.x); o.y = (uint16_t)f2bs(vv.y);
      o.z = (uint16_t)f2bs(vv.z); o.w = (uint16_t)f2bs(vv.w);
    } else {
      const uint32_t* s = w + (base >> 1);
      uint32_t w0 = s[0], w1 = s[1];
      o.x = (uint16_t)(w0 & 0xffffu); o.y = (uint16_t)(w0 >> 16);
      o.z = (uint16_t)(w1 & 0xffffu); o.w = (uint16_t)(w1 >> 16);
    }
    *(ushort4*)((uint16_t*)(ws + offs[t]) + base) = o;
  } else {
    float* dst = ws + offs[t];
    if (sf) {
      *(float4*)(dst + base) = *(const float4*)((const float*)w + base);
    } else {
      const uint32_t* s = w + (base >> 1);
      uint32_t w0 = s[0], w1 = s[1];
      float4 o;
      o.x = __uint_as_float((w0 & 0xffffu) << 16);
      o.y = __uint_as_float(w0 & 0xffff0000u);
      o.z = __uint_as_float((w1 & 0xffffu) << 16);
      o.w = __uint_as_float(w1 & 0xffff0000u);
      *(float4*)(dst + base) = o;
    }
  }
}

// ---------------- W2 = IPW(2320x512) @ CWT(192x512)^T -> bf16 [e][k'] ----------------
// 2-phase K staging. Plus blocks 111..120: bias2[e] = IPW.cb, and ZX cls rows.
__global__ __launch_bounds__(256) void k_w2(const uint16_t* __restrict__ IPW,
                                            const uint16_t* __restrict__ CWT,
                                            const float* __restrict__ cb,
                                            const float* __restrict__ cls,
                                            uint16_t* __restrict__ W2,
                                            float* __restrict__ bias2,
                                            uint16_t* __restrict__ ZX) {
  int bx = blockIdx.x;
  int tid = threadIdx.x;

  if (bx >= 111) {                                  // bias2 + cls rows
    __shared__ float scb[512];
    __shared__ float scl[512];
    for (int i = tid; i < 512; i += 256) {
      scb[i] = cb[i];
      scl[i] = bf2f((uint16_t)f2bs(cls[i]));        // cls via bf16 (match old H path)
    }
    __syncthreads();
    int e = (bx - 111) * 232 + tid;
    if (tid < 232 && e < 2320) {
      float sb = 0.f, sc = 0.f;
      for (int d8 = 0; d8 < 512; d8 += 8) {
        ushortx8 v = *(const ushortx8*)(IPW + (long)e * 512 + d8);
#pragma unroll
        for (int j = 0; j < 8; ++j) {
          float wv = bf2f(v[j]);
          sb = fmaf(wv, scb[d8 + j], sb);
          sc = fmaf(wv, scl[d8 + j], sc);
        }
      }
      bias2[e] = sb;
      uint16_t cz = (uint16_t)f2bs(sc);
      ZX[(long)1024 * EPROJ + e] = cz;              // b=0 cls row
      ZX[(long)2049 * EPROJ + e] = cz;              // b=1 cls row (same value)
    }
    return;
  }

  int bm = bx / 3, bn = bx % 3;                     // 37 x 3 tiles of 64x64
  __shared__ __align__(16) short sA[64 * 264];
  __shared__ __align__(16) short sB[64 * 264];
  int lane = tid & 63, w = tid >> 6, lm = lane & 15, q = lane >> 4;

  floatx4 acc[4] = {};
  for (int ph = 0; ph < 2; ++ph) {                  // K = 2 x 256
    int d0 = ph * 256;
#pragma unroll
    for (int it = 0; it < 8; ++it) {
      int li = it * 256 + tid;                      // 0..2047
      int row = li >> 5, col = (li & 31) * 8;
      int ge = bm * 64 + row;
      ushortx8 av = {0,0,0,0,0,0,0,0};
      if (ge < 2320) av = *(const ushortx8*)(IPW + (long)ge * 512 + d0 + col);
      *(ushortx8*)&sA[row * 264 + col] = av;
      ushortx8 bv = *(const ushortx8*)(CWT + (long)(bn * 64 + row) * 512 + d0 + col);
      *(ushortx8*)&sB[row * 264 + col] = bv;
    }
    __syncthreads();
#pragma unroll
    for (int kk = 0; kk < 8; ++kk) {
      short8 a = *(const short8*)&sA[(w * 16 + lm) * 264 + kk * 32 + q * 8];
#pragma unroll
      for (int ct = 0; ct < 4; ++ct) {
        short8 b = *(const short8*)&sB[(ct * 16 + lm) * 264 + kk * 32 + q * 8];
        acc[ct] = __builtin_amdgcn_mfma_f32_16x16x32_bf16(a, b, acc[ct], 0, 0, 0);
      }
    }
    __syncthreads();
  }
#pragma unroll
  for (int reg = 0; reg < 4; ++reg) {
    int e = bm * 64 + w * 16 + q * 4 + reg;
    if (e < 2320) {
#pragma unroll
      for (int ct = 0; ct < 4; ++ct)
        W2[(long)e * 192 + bn * 64 + ct * 16 + lm] = (uint16_t)f2bs(acc[ct][reg]);
    }
  }
}

// ---------------- in_proj (fused with conv-embed): ZX = X3 @ W2^T + bias2 ----------------
__global__ __launch_bounds__(256) void k_ipgemm(const uint16_t* __restrict__ X3,
                                                const uint16_t* __restrict__ W2,
                                                const float* __restrict__ bias2,
                                                const uint8_t* __restrict__ keep,
                                                uint16_t* __restrict__ ZX) {
  __shared__ __align__(16) short sA[64 * 200];
  __shared__ __align__(16) short sB[64 * 200];
  __shared__ uint8_t skp[64];
  int tid = threadIdx.x;
  int lane = tid & 63, w = tid >> 6, lm = lane & 15, q = lane >> 4;
  int bm = blockIdx.y * 64, bn = blockIdx.x * 64;

  if (tid < 64) {
    int rr = bm + tid;
    skp[tid] = keep[(rr >> 10) * LTOK + (rr & 1023)];
  }
#pragma unroll
  for (int it = 0; it < 6; ++it) {
    int li = it * 256 + tid;                        // 0..1535
    int row = li / 24, col = (li % 24) * 8;
    ushortx8 av = *(const ushortx8*)(X3 + (long)(bm + row) * 192 + col);
    *(ushortx8*)&sA[row * 200 + col] = av;
    int gn = bn + row;
    ushortx8 bv = {0,0,0,0,0,0,0,0};
    if (gn < 2320) bv = *(const ushortx8*)(W2 + (long)gn * 192 + col);
    *(ushortx8*)&sB[row * 200 + col] = bv;
  }
  __syncthreads();

  floatx4 acc[4] = {};
#pragma unroll
  for (int kb = 0; kb < 6; ++kb) {
    short8 a = *(const short8*)&sA[(w * 16 + lm) * 200 + kb * 32 + q * 8];
#pragma unroll
    for (int ct = 0; ct < 4; ++ct) {
      short8 b = *(const short8*)&sB[(ct * 16 + lm) * 200 + kb * 32 + q * 8];
      acc[ct] = __builtin_amdgcn_mfma_f32_16x16x32_bf16(a, b, acc[ct], 0, 0, 0);
    }
  }
#pragma unroll
  for (int reg = 0; reg < 4; ++reg) {
    int r = bm + w * 16 + q * 4 + reg;              // body index 0..2047
    long crow = (long)((r >> 10) * LTOK + (r & 1023));   // cls-gap remap
    int kp = skp[r - bm];
#pragma unroll
    for (int ct = 0; ct < 4; ++ct) {
      int e = bn + ct * 16 + lm;
      if (e < 2320 && (e >= DIN || kp))
        ZX[crow * EPROJ + e] = (uint16_t)f2bs(acc[ct][reg] + bias2[e]);
    }
  }
}

// ---------------- depthwise causal conv(4) + silu (+ fused dt/lga) ----------------
// 320 threads/block: 320 c4-slots for CDIM=1280 -> every thread exactly one slot
// (was 256 threads: wave 0 ran the loop twice while waves 1-3 idled).
__global__ __launch_bounds__(320) void k_conv1d(const uint16_t* __restrict__ zx,
                                                const float* __restrict__ w,
                                                const float* __restrict__ bias,
                                                uint16_t* __restrict__ xbc,
                                                const float* __restrict__ dtb,
                                                const float* __restrict__ alog,
                                                float* __restrict__ dt,
                                                float* __restrict__ lga) {
  int g = blockIdx.x;
  int tid = threadIdx.x;
  if (g >= 514) {                        // fused dt/lga: blocks 514..642 (256-wide indexing)
    if (tid < 256) {
      int idx = (g - 514) * 256 + tid;
      if (idx < NROWS * NHEAD) {
        int rr = idx >> 4, h = idx & 15;
        float xv = bf2f(zx[(long)rr * EPROJ + (EPROJ - NHEAD) + h]) + dtb[h];
        float dtv = (xv > 20.f) ? xv : log1pf(expf(xv));
        dt[idx] = dtv;
        lga[idx] = dtv * (-expf(alog[h]));
      }
    }
    return;
  }
  // bijective XCD swizzle for 514 groups (8 XCDs: q=64, rem=2)
  {
    int xcd = g & 7, slot = g >> 3;
    g = (xcd < 2) ? xcd * 65 + slot : 130 + (xcd - 2) * 64 + slot;
  }
  int b = g / 257, gi = g % 257;
  int t0 = gi * 4;
  int nr = (t0 == 1024) ? 1 : 4;
  const uint16_t* zrow = zx + (long)b * LTOK * EPROJ + DIN;
  int c4 = tid * 4;                      // exactly one slot per thread
  {
    float4 bi = *(const float4*)(bias + c4);
    float4 w0 = *(const float4*)(w + (c4 + 0) * 4);
    float4 w1 = *(const float4*)(w + (c4 + 1) * 4);
    float4 w2 = *(const float4*)(w + (c4 + 2) * 4);
    float4 w3 = *(const float4*)(w + (c4 + 3) * 4);
    float wr[4][4] = {{w0.x, w0.y, w0.z, w0.w}, {w1.x, w1.y, w1.z, w1.w},
                      {w2.x, w2.y, w2.z, w2.w}, {w3.x, w3.y, w3.z, w3.w}};
    float acc[4][4];                     // [row][chan]
#pragma unroll
    for (int ri = 0; ri < 4; ++ri) {
      acc[ri][0] = bi.x; acc[ri][1] = bi.y; acc[ri][2] = bi.z; acc[ri][3] = bi.w;
    }
#pragma unroll
    for (int dtt = -3; dtt <= 3; ++dtt) {
      int tt = t0 + dtt;
      if (tt < 0 || tt > 1024) continue;
      ushort4 xv = *(const ushort4*)(zrow + (long)tt * EPROJ + c4);
      float x0 = bf2f(xv.x), x1 = bf2f(xv.y), x2 = bf2f(xv.z), x3 = bf2f(xv.w);
#pragma unroll
      for (int ri = 0; ri < 4; ++ri) {
        int k = dtt - ri + 3;            // tap index for output row t0+ri
        if (k >= 0 && k <= 3) {
          acc[ri][0] = fmaf(wr[0][k], x0, acc[ri][0]);
          acc[ri][1] = fmaf(wr[1][k], x1, acc[ri][1]);
          acc[ri][2] = fmaf(wr[2][k], x2, acc[ri][2]);
          acc[ri][3] = fmaf(wr[3][k], x3, acc[ri][3]);
        }
      }
    }
#pragma unroll
    for (int ri = 0; ri < 4; ++ri) {
      if (ri < nr) {
        long r = (long)b * LTOK + t0 + ri;
        ushort4 o;
        o.x = (uint16_t)f2bs(acc[ri][0] / (1.f + __expf(-acc[ri][0])));
        o.y = (uint16_t)f2bs(acc[ri][1] / (1.f + __expf(-acc[ri][1])));
        o.z = (uint16_t)f2bs(acc[ri][2] / (1.f + __expf(-acc[ri][2])));
        o.w = (uint16_t)f2bs(acc[ri][3] / (1.f + __expf(-acc[ri][3])));
        *(ushort4*)(xbc + r * CDIM + c4) = o;
      }
    }
  }
}

// ---------------- SSD phase 1: chunk states only (SL bf16, CLA) ----------------
// X staging hoisted before the scan barrier: waves 1-3 stage X while wave 0 scans.
__global__ __launch_bounds__(256) void k_ssd1(const uint16_t* __restrict__ xbc,
                                              const float* __restrict__ dt,
                                              const float* __restrict__ lga,
                                              uint16_t* __restrict__ SL,
                                              float* __restrict__ CLA) {
  int blk = blockIdx.x;
  int c = blk % NCH;
  int hh = blk / NCH;            // h + 16*b
  int h = hh & 15, b = hh >> 4;
  int tid = threadIdx.x;
  int lane = tid & 63, w = tid >> 6;
  int lm = lane & 15, q = lane >> 4;

  __shared__ __align__(16) short sBT[128 * 72];
  __shared__ __align__(16) short sXT[64 * 72];
  __shared__ float wwv[64];

  int t0 = c * QC;
  const uint16_t* base = xbc + (long)b * LTOK * CDIM;

  if (tid < 64) {                // wave 0: loads + parallel inclusive scan
    int t = t0 + tid;
    float dtv = (t < LTOK) ? dt[((long)(b * LTOK + t)) * NHEAD + h] : 0.f;
    float v   = (t < LTOK) ? lga[((long)(b * LTOK + t)) * NHEAD + h] : 0.f;
#pragma unroll
    for (int off = 1; off < 64; off <<= 1) {
      float u = __shfl_up(v, off, 64);
      if (lane >= off) v += u;
    }
    float clEnd = __shfl(v, 63, 64);
    wwv[tid] = __expf(clEnd - v) * dtv;
    CLA[(long)blk * 64 + tid] = v;
  }
  // X staging (no wwv dependency) overlaps wave-0's scan
#pragma unroll
  for (int k = 0; k < 4; ++k) {
    int e4 = (tid + k * 256) * 4;
    int row = e4 >> 6, col = e4 & 63;
    int t = t0 + row;
    ushort4 xv = {0,0,0,0};
    if (t < LTOK) xv = *(const ushort4*)(base + (long)t * CDIM + h * 64 + col);
    sXT[(col  )*72+row]=(short)xv.x; sXT[(col+1)*72+row]=(short)xv.y;
    sXT[(col+2)*72+row]=(short)xv.z; sXT[(col+3)*72+row]=(short)xv.w;
  }
  __syncthreads();               // wwv visible

#pragma unroll
  for (int k = 0; k < 8; ++k) {
    int e4 = (tid + k * 256) * 4;
    int row = e4 >> 7, col = e4 & 127;
    int t = t0 + row;
    ushort4 bv = {0,0,0,0};
    if (t < LTOK) bv = *(const ushort4*)(base + (long)t * CDIM + DIN + col);
    float wv = wwv[row];
    sBT[(col  )*72+row]=f2bs(bf2f(bv.x)*wv); sBT[(col+1)*72+row]=f2bs(bf2f(bv.y)*wv);
    sBT[(col+2)*72+row]=f2bs(bf2f(bv.z)*wv); sBT[(col+3)*72+row]=f2bs(bf2f(bv.w)*wv);
  }
  __syncthreads();

  floatx4 s[2][4] = {};
#pragma unroll
  for (int kb = 0; kb < 2; ++kb) {
    short8 bfr[4];
#pragma unroll
    for (int ct = 0; ct < 4; ++ct)
      bfr[ct] = *(const short8*)&sXT[(ct*16 + lm)*72 + kb*32 + q*8];
#pragma unroll
    for (int nt = 0; nt < 2; ++nt) {
      short8 a = *(const short8*)&sBT[((w*2+nt)*16 + lm)*72 + kb*32 + q*8];
#pragma unroll
      for (int ct = 0; ct < 4; ++ct)
        s[nt][ct] = __builtin_amdgcn_mfma_f32_16x16x32_bf16(a, bfr[ct], s[nt][ct], 0, 0, 0);
    }
  }
  uint16_t* slp = SL + (long)blk * 8192;
#pragma unroll
  for (int nt = 0; nt < 2; ++nt)
#pragma unroll
    for (int ct = 0; ct < 4; ++ct)
#pragma unroll
      for (int reg = 0; reg < 4; ++reg) {
        int n = (w*2+nt)*16 + q*4 + reg;
        int p = ct*16 + lm;
        slp[n*64 + p] = (uint16_t)f2bs(s[nt][ct][reg]);
      }
}

// ---------------- SSD phase 2a: prefix scan over chunks (bf16 in, f32 scan, bf16 out) ----------------
__global__ __launch_bounds__(256) void k_comb(const uint16_t* __restrict__ SL,
                                              const float* __restrict__ CLA,
                                              uint16_t* __restrict__ SL2) {
  int bx = blockIdx.x;
  int piece = bx & 15;
  int hh = bx >> 4;
  int off = piece * 512 + threadIdx.x * 2;
  long cb0 = (long)hh * NCH;
  float P[NCH];
  float2 tmp[NCH];
#pragma unroll
  for (int c = 0; c < NCH; ++c) {
    P[c] = __expf(CLA[(cb0 + c) * 64 + 63]);
    uint32_t pk = *(const uint32_t*)(SL + (cb0 + c) * 8192 + off);
    tmp[c].x = bf2f((uint16_t)(pk & 0xffffu));
    tmp[c].y = bf2f((uint16_t)(pk >> 16));
  }
  float2 s = make_float2(0.f, 0.f);
#pragma unroll
  for (int c = 0; c < NCH; ++c) {
    uint32_t packed = (uint32_t)(uint16_t)f2bs(s.x) | ((uint32_t)(uint16_t)f2bs(s.y) << 16);
    *(uint32_t*)(SL2 + (cb0 + c) * 8192 + off) = packed;
    s.x = fmaf(P[c], s.x, tmp[c].x);
    s.y = fmaf(P[c], s.y, tmp[c].y);
  }
}

// ---------------- SSD phase 2b: FULL Y, B/C fragments direct from global ----------------
__global__ __launch_bounds__(256) void k_ssd3(const uint16_t* __restrict__ xbc,
                                              const float* __restrict__ dt,
                                              const uint16_t* __restrict__ SL2,
                                              const float* __restrict__ CLA,
                                              const uint8_t* __restrict__ keepf,
                                              float* __restrict__ Y) {
  int blk = blockIdx.x;
  int c = blk % NCH;
  int hh = blk / NCH;
  int h = hh & 15, b = hh >> 4;
  int tid = threadIdx.x;
  int lane = tid & 63, w = tid >> 6;
  int lm = lane & 15, q = lane >> 4;

  __shared__ __align__(16) short sST[64 * 136];   // S^T[p][n]
  __shared__ __align__(16) short sXT[64 * 72];    // X^T[p][t]
  __shared__ __align__(16) short sM[64 * 72];     // M[tl][tp]
  __shared__ float dtw[64], clA[64], evec[64];
  __shared__ uint8_t kf[64];

  int t0 = c * QC;
  const uint16_t* base = xbc + (long)b * LTOK * CDIM;
  const uint16_t* slp = SL2 + (long)blk * 8192;

  if (tid < 64) {
    int t = t0 + tid;
    dtw[tid] = (t < LTOK) ? dt[((long)(b * LTOK + t)) * NHEAD + h] : 0.f;
    float v = CLA[(long)blk * 64 + tid];
    clA[tid] = v;
    evec[tid] = __expf(v);
    kf[tid] = (t < LTOK) ? keepf[b * LTOK + t] : 0;
  }

#pragma unroll
  for (int k = 0; k < 4; ++k) {
    int e4 = (tid + k * 256) * 4;
    int row = e4 >> 6, col = e4 & 63;
    int t = t0 + row;
    ushort4 xv = {0,0,0,0};
    if (t < LTOK) xv = *(const ushort4*)(base + (long)t * CDIM + h * 64 + col);
    sXT[(col  )*72+row]=(short)xv.x; sXT[(col+1)*72+row]=(short)xv.y;
    sXT[(col+2)*72+row]=(short)xv.z; sXT[(col+3)*72+row]=(short)xv.w;
  }
#pragma unroll
  for (int k = 0; k < 8; ++k) {
    int e4 = (tid + k * 256) * 4;
    int n = e4 >> 6, p = e4 & 63;
    ushort4 sv = *(const ushort4*)(slp + n * 64 + p);
    sST[(p  )*136+n]=(short)sv.x; sST[(p+1)*136+n]=(short)sv.y;
    sST[(p+2)*136+n]=(short)sv.z; sST[(p+3)*136+n]=(short)sv.w;
  }
  __syncthreads();     // staging + wave0 init visible

  // C fragments (registers) — shared between G and y2 matmuls; direct global (L2-hot)
  short8 cfr[4];
  int tA = t0 + w*16 + lm;
  bool tAok = tA < LTOK;
#pragma unroll
  for (int kb = 0; kb < 4; ++kb) {
    short8 z = {0,0,0,0,0,0,0,0};
    cfr[kb] = tAok ? *(const short8*)(base + (long)tA * CDIM + DIN + DST + kb*32 + q*8) : z;
  }

  // G = C . B^T : B fragments direct from global
  floatx4 g[4] = {};
#pragma unroll
  for (int kb = 0; kb < 4; ++kb) {
#pragma unroll
    for (int ct = 0; ct < 4; ++ct) {
      int tB = t0 + ct*16 + lm;
      short8 z = {0,0,0,0,0,0,0,0};
      short8 bb = (tB < LTOK) ? *(const short8*)(base + (long)tB * CDIM + DIN + kb*32 + q*8) : z;
      g[ct] = __builtin_amdgcn_mfma_f32_16x16x32_bf16(cfr[kb], bb, g[ct], 0, 0, 0);
    }
  }
  // M[tl][tp] = tril(G) * exp(clA[tl]-clA[tp]) * dt[tp]
#pragma unroll
  for (int ct = 0; ct < 4; ++ct) {
    int tp = ct*16 + lm;
#pragma unroll
    for (int reg = 0; reg < 4; ++reg) {
      int tl = w*16 + q*4 + reg;
      float m = 0.f;
      if (tp <= tl) m = g[ct][reg] * __expf(clA[tl] - clA[tp]) * dtw[tp];
      sM[tl*72 + tp] = f2bs(m);
    }
  }
  // cross-chunk: y2 = C . S_start^T (overlaps the sM barrier)
  floatx4 y2[4] = {};
#pragma unroll
  for (int kb = 0; kb < 4; ++kb) {
#pragma unroll
    for (int ct = 0; ct < 4; ++ct) {
      short8 bb = *(const short8*)&sST[(ct*16 + lm)*136 + kb*32 + q*8];
      y2[ct] = __builtin_amdgcn_mfma_f32_16x16x32_bf16(cfr[kb], bb, y2[ct], 0, 0, 0);
    }
  }
  __syncthreads();     // sM visible
  // within-chunk: y1 = M . X
  floatx4 y1[4] = {};
#pragma unroll
  for (int kb = 0; kb < 2; ++kb) {
    short8 a = *(const short8*)&sM[(w*16 + lm)*72 + kb*32 + q*8];
#pragma unroll
    for (int ct = 0; ct < 4; ++ct) {
      short8 bb = *(const short8*)&sXT[(ct*16 + lm)*72 + kb*32 + q*8];
      y1[ct] = __builtin_amdgcn_mfma_f32_16x16x32_bf16(a, bb, y1[ct], 0, 0, 0);
    }
  }
#pragma unroll
  for (int reg = 0; reg < 4; ++reg) {
    int tl = w*16 + q*4 + reg;
    int t = t0 + tl;
    if (t < LTOK && kf[tl]) {
      float ev = evec[tl];
#pragma unroll
      for (int ct = 0; ct < 4; ++ct) {
        int p = ct*16 + lm;
        Y[((long)(b * LTOK + t)) * DIN + h * 64 + p] = y1[ct][reg] + ev * y2[ct][reg];
      }
    }
  }
}

// ---------------- gathered rows only: y(+D*x) + gate silu(z) + RMSNorm -> bf16 ----------------
__global__ __launch_bounds__(256) void k_gaterms(const float* __restrict__ Y,
                                                 const uint16_t* __restrict__ xbc,
                                                 const uint16_t* __restrict__ zx,
                                                 const float* __restrict__ Dv,
                                                 const float* __restrict__ rmsw,
                                                 const int* __restrict__ ridx,
                                                 uint16_t* __restrict__ G) {
  int rr = blockIdx.x;
  long r = ridx[rr];
  int tid = threadIdx.x;
  int e = tid * 4;
  int h = tid >> 4;
  float4 a = *(const float4*)(Y + r * DIN + e);
  const ushort4 xu = *(const ushort4*)(xbc + r * CDIM + e);
  const ushort4 zu = *(const ushort4*)(zx + r * EPROJ + e);
  float Dh = Dv[h];
  float y0 = a.x + Dh * bf2f(xu.x), y1 = a.y + Dh * bf2f(xu.y);
  float y2 = a.z + Dh * bf2f(xu.z), y3 = a.w + Dh * bf2f(xu.w);
  float z0 = bf2f(zu.x), z1 = bf2f(zu.y), z2 = bf2f(zu.z), z3 = bf2f(zu.w);
  float g0 = y0 * (z0 / (1.f + expf(-z0)));
  float g1 = y1 * (z1 / (1.f + expf(-z1)));
  float g2 = y2 * (z2 / (1.f + expf(-z2)));
  float g3 = y3 * (z3 / (1.f + expf(-z3)));
  __shared__ float red[256];
  red[tid] = g0*g0 + g1*g1 + g2*g2 + g3*g3;
  __syncthreads();
  for (int st = 128; st; st >>= 1) {
    if (tid < st) red[tid] += red[tid + st];
    __syncthreads();
  }
  float scale = rsqrtf(red[0] * (1.0f / 1024.0f) + 1e-5f);
  float4 rw = *(const float4*)(rmsw + e);
  ushort4 o;
  o.x = (uint16_t)f2bs(g0 * scale * rw.x);
  o.y = (uint16_t)f2bs(g1 * scale * rw.y);
  o.z = (uint16_t)f2bs(g2 * scale * rw.z);
  o.w = (uint16_t)f2bs(g3 * scale * rw.w);
  *(ushort4*)(G + (long)rr * DIN + e) = o;
}

// ---------------- out_proj GEMM, one-shot K-slice, no atomics ----------------
__global__ __launch_bounds__(256) void k_ogemm(const uint16_t* __restrict__ A,
                                               const uint16_t* __restrict__ Bw,
                                               float* __restrict__ OUTP) {
  __shared__ __align__(16) short sA[64 * 264];
  __shared__ __align__(16) short sB[64 * 264];
  int tid = threadIdx.x;
  int lane = tid & 63, w = tid >> 6;
  int lm = lane & 15, q = lane >> 4;
  int bm = blockIdx.y * 64, bn = blockIdx.x * 64;
  int kbase = blockIdx.z * 256;

#pragma unroll
  for (int it = 0; it < 8; ++it) {
    int li = it * 256 + tid;              // 0..2047
    int row = li >> 5, col = (li & 31) * 8;
    int gm = bm + row;
    ushortx8 av = {0,0,0,0,0,0,0,0};
    if (gm < 514) av = *(const ushortx8*)(A + (long)gm * 1024 + kbase + col);
    *(ushortx8*)&sA[row * 264 + col] = av;
    ushortx8 bv = *(const ushortx8*)(Bw + (long)(bn + row) * 1024 + kbase + col);
    *(ushortx8*)&sB[row * 264 + col] = bv;
  }
  __syncthreads();

  floatx4 acc[4] = {};
#pragma unroll
  for (int kb = 0; kb < 8; ++kb) {
    short8 a = *(const short8*)&sA[(w * 16 + lm) * 264 + kb * 32 + q * 8];
#pragma unroll
    for (int ct = 0; ct < 4; ++ct) {
      short8 b = *(const short8*)&sB[(ct * 16 + lm) * 264 + kb * 32 + q * 8];
      acc[ct] = __builtin_amdgcn_mfma_f32_16x16x32_bf16(a, b, acc[ct], 0, 0, 0);
    }
  }
  float* op = OUTP + (long)blockIdx.z * 263168;
#pragma unroll
  for (int reg = 0; reg < 4; ++reg) {
    int r = bm + w * 16 + q * 4 + reg;
    if (r < 514) {
#pragma unroll
      for (int ct = 0; ct < 4; ++ct)
        op[(long)r * 512 + bn + ct * 16 + lm] = acc[ct][reg];
    }
  }
}

// ---------------- final LayerNorm (sums 4 out_proj partials) -> f32 out ----------------
__global__ __launch_bounds__(256) void k_ln(const float* __restrict__ outp,
                                            const float* __restrict__ lng,
                                            const float* __restrict__ lnb,
                                            float* __restrict__ out) {
  int r = blockIdx.x;
  int tid = threadIdx.x;
  long e = (long)r * DM + tid * 2;
  float2 v0 = *(const float2*)(outp + e);
  float2 v1 = *(const float2*)(outp + 263168 + e);
  float2 v2 = *(const float2*)(outp + 2 * 263168 + e);
  float2 v3 = *(const float2*)(outp + 3 * 263168 + e);
  float2 v;
  v.x = ((v0.x + v1.x) + v2.x) + v3.x;
  v.y = ((v0.y + v1.y) + v2.y) + v3.y;
  __shared__ float red[256];
  red[tid] = v.x + v.y;
  __syncthreads();
  for (int st = 128; st; st >>= 1) { if (tid < st) red[tid] += red[tid + st]; __syncthreads(); }
  float mu = red[0] * (1.0f / 512.0f);
  __syncthreads();
  float dx = v.x - mu, dy = v.y - mu;
  red[tid] = dx * dx + dy * dy;
  __syncthreads();
  for (int st = 128; st; st >>= 1) { if (tid < st) red[tid] += red[tid + st]; __syncthreads(); }
  float sc = rsqrtf(red[0] * (1.0f / 512.0f) + 1e-5f);
  int c = tid * 2;
  out[(long)r * DM + c]     = dx * sc * lng[c] + lnb[c];
  out[(long)r * DM + c + 1] = dy * sc * lng[c + 1] + lnb[c + 1];
}

// ---------------- launch ----------------
extern "C" void kernel_launch(void* const* d_in, const int* in_sizes, int n_in,
                              void* d_out, int out_size, void* d_ws, size_t ws_size,
                              hipStream_t stream) {
  float* ws = (float*)d_ws;
  float* out = (float*)d_out;
  int* rowidx = (int*)(ws + O_RIDX);
  InPtrs ip;
  for (int i = 0; i < 14; ++i) ip.p[i] = d_in[i];

  // convert (+CWT reorder) + RNG/keep + vectorized im2col (k' layout)
  hipLaunchKernelGGL(k_convert, dim3(2071), dim3(256), 0, stream, ip, ws, out, rowidx);
  // W2 = IPW @ CW (fused conv-embed x in_proj weights, k' order) + bias2 + cls ZX rows
  hipLaunchKernelGGL(k_w2, dim3(121), dim3(256), 0, stream,
                     (const uint16_t*)(ws + O_IPW), (const uint16_t*)(ws + O_CWT),
                     ws + O_CB, ws + O_CLS,
                     (uint16_t*)(ws + O_W2), ws + O_BIAS2, (uint16_t*)(ws + O_ZX));
  // in_proj fused GEMM: ZX body = X3 @ W2^T + bias2 (one-shot K=192, keep-masked z)
  hipLaunchKernelGGL(k_ipgemm, dim3(37, 32), dim3(256), 0, stream,
                     (const uint16_t*)(ws + O_X3), (const uint16_t*)(ws + O_W2),
                     ws + O_BIAS2, (const uint8_t*)(ws + O_KEEP),
                     (uint16_t*)(ws + O_ZX));
  // conv + silu (bf16 zx -> bf16 xbc), 4 rows/block, 320 threads + dt/lga blocks
  hipLaunchKernelGGL(k_conv1d, dim3(643), dim3(320), 0, stream,
                     (const uint16_t*)(ws + O_ZX), ws + O_C1W, ws + O_C1B,
                     (uint16_t*)(ws + O_XBC),
                     ws + O_DTB, ws + O_ALOG, ws + O_DT, ws + O_LGA);
  // phase 1: chunk states (bf16) + cumsum
  hipLaunchKernelGGL(k_ssd1, dim3(32 * NCH), dim3(256), 0, stream,
                     (const uint16_t*)(ws + O_XBC), ws + O_DT, ws + O_LGA,
                     (uint16_t*)(ws + O_SL), ws + O_CLA);
  // phase 2a: prefix states (bf16 in/out, f32 scan)
  hipLaunchKernelGGL(k_comb, dim3(512), dim3(256), 0, stream,
                     (const uint16_t*)(ws + O_SL), ws + O_CLA, (uint16_t*)(ws + O_SL2));
  // phase 2b: full Y (within + cross chunk), keep-masked single write
  hipLaunchKernelGGL(k_ssd3, dim3(32 * NCH), dim3(256), 0, stream,
                     (const uint16_t*)(ws + O_XBC), ws + O_DT,
                     (const uint16_t*)(ws + O_SL2), ws + O_CLA,
                     (const uint8_t*)(ws + O_KEEP), ws + O_Y);
  // gather(514) + gate + RMS -> bf16 into dead X3 buffer
  hipLaunchKernelGGL(k_gaterms, dim3(514), dim3(256), 0, stream,
                     ws + O_Y, (const uint16_t*)(ws + O_XBC),
                     (const uint16_t*)(ws + O_ZX), ws + O_DV, ws + O_RMSW,
                     (const int*)rowidx, (uint16_t*)(ws + O_X3));
  // out_proj GEMM: one-shot K-slices, no atomics, 288 blocks -> 4 f32 partials
  hipLaunchKernelGGL(k_ogemm, dim3(8, 9, 4), dim3(256), 0, stream,
                     (const uint16_t*)(ws + O_X3), (const uint16_t*)(ws + O_OPW),
                     ws + O_OUTP);
  // LN sums the 4 partials inline
  hipLaunchKernelGGL(k_ln, dim3(514), dim3(256), 0, stream,
                     ws + O_OUTP, ws + O_LNG, ws + O_LNB, out);
}